// Round 5
// baseline (287.835 us; speedup 1.0000x reference)
//
#include <hip/hip_runtime.h>
#include <hip/hip_bf16.h>

// MultiHeadAttention (single-head, full-width, MULTIPLICATIVE tril mask)
// B=4, T=2048, D=1024. fp32 in/out; bf16 MFMA internally.
//
// Pipeline (all in d_ws):
//   1) cast x -> xb (bf16)                                   16 MiB
//   2) transpose+cast w_q/w_k/w_v -> wt[3] (bf16, N-major)     6 MiB
//   3) GEMM qkv: qb (gamma-folded), kb, vt (V transposed)    48 MiB
//   4) GEMM scores: S = q.k^T, masked (j>i -> exact 0), bf16 32 MiB
//   5) row softmax over full 2048 row (masked zeros count!)
//   6) GEMM pv: out = P @ V (fp32 out)

typedef float  f32x4   __attribute__((ext_vector_type(4)));
typedef __bf16 bf16x8v __attribute__((ext_vector_type(8)));

#define GLOAD_LDS16(g, l) __builtin_amdgcn_global_load_lds(                  \
    (const __attribute__((address_space(1))) void*)(g),                      \
    (__attribute__((address_space(3))) void*)(l), 16, 0, 0)

static constexpr int BB = 4, TT = 2048, DD = 1024;

// ---------------------------------------------------------------- staging
// Stage a 128x64 bf16 tile (row stride = ldg elems) into linear LDS [128][64].
// 256 threads x 4 issues x 16B. LDS dest is wave-uniform base + lane*16.
__device__ __forceinline__ void stage_tile_128x64(const __bf16* g0, int ldg,
                                                  __bf16* lds) {
  const int t = threadIdx.x;
  const int w = t >> 6;
#pragma unroll
  for (int i = 0; i < 4; ++i) {
    const int row = i * 32 + (t >> 3);
    const int col = (t & 7) * 8;
    const __bf16* g = g0 + (size_t)row * ldg + col;
    __bf16* l = lds + i * 2048 + w * 512;  // wave-uniform base
    GLOAD_LDS16(g, l);
  }
}

// ---------------------------------------------------------------- mainloop
// 128x128 output tile, 4 waves (2x2), each wave 64x64 = 4x4 frags of 16x16.
// A0: tile origin [row0][0] (lda elems/row). B0: B^T tile origin [col0][0].
__device__ __forceinline__ void gemm_mainloop(const __bf16* A0, int lda,
                                              const __bf16* B0, int ldb, int K,
                                              __bf16* lsA, __bf16* lsB,
                                              f32x4 acc[4][4]) {
  const int t = threadIdx.x;
  const int lane = t & 63;
  const int w = t >> 6;
  const int wr = (w >> 1) * 64, wc = (w & 1) * 64;
  const int fr = lane & 15, fq = lane >> 4;

  for (int k0 = 0; k0 < K; k0 += 64) {
    __syncthreads();  // previous compute done before LDS overwrite
    stage_tile_128x64(A0 + k0, lda, lsA);
    stage_tile_128x64(B0 + k0, ldb, lsB);
    __syncthreads();  // vmcnt(0) drain: staged data visible
#pragma unroll
    for (int ks = 0; ks < 2; ++ks) {
      bf16x8v af[4], bf[4];
#pragma unroll
      for (int m = 0; m < 4; ++m)
        af[m] = *reinterpret_cast<const bf16x8v*>(
            &lsA[(wr + m * 16 + fr) * 64 + ks * 32 + fq * 8]);
#pragma unroll
      for (int n = 0; n < 4; ++n)
        bf[n] = *reinterpret_cast<const bf16x8v*>(
            &lsB[(wc + n * 16 + fr) * 64 + ks * 32 + fq * 8]);
#pragma unroll
      for (int m = 0; m < 4; ++m)
#pragma unroll
        for (int n = 0; n < 4; ++n)
          acc[m][n] = __builtin_amdgcn_mfma_f32_16x16x32_bf16(
              af[m], bf[n], acc[m][n], 0, 0, 0);
    }
  }
}

// ---------------------------------------------------------------- kernels
__global__ __launch_bounds__(256) void k_cast_x(const float4* __restrict__ x,
                                                bf16x8v* __restrict__ xb,
                                                int n8) {
  // n8 = total elems / 8; each iteration converts 8 floats -> 8 bf16.
  for (int i = blockIdx.x * 256 + threadIdx.x; i < n8; i += gridDim.x * 256) {
    float4 a = x[i * 2], b = x[i * 2 + 1];
    bf16x8v o;
    o[0] = (__bf16)a.x; o[1] = (__bf16)a.y; o[2] = (__bf16)a.z; o[3] = (__bf16)a.w;
    o[4] = (__bf16)b.x; o[5] = (__bf16)b.y; o[6] = (__bf16)b.z; o[7] = (__bf16)b.w;
    xb[i] = o;
  }
}

__global__ __launch_bounds__(1024) void k_transpose_w(
    const float* __restrict__ wq, const float* __restrict__ wk,
    const float* __restrict__ wv, __bf16* __restrict__ wt) {
  __shared__ __bf16 tile[32][33];
  const float* w = (blockIdx.z == 0) ? wq : (blockIdx.z == 1) ? wk : wv;
  const int n0 = blockIdx.x * 32, k0 = blockIdx.y * 32;
  const int tx = threadIdx.x, ty = threadIdx.y;
  tile[ty][tx] = (__bf16)w[(size_t)(k0 + ty) * DD + n0 + tx];
  __syncthreads();
  // wt[z][n][k] = w[k][n]
  wt[(size_t)blockIdx.z * DD * DD + (size_t)(n0 + ty) * DD + k0 + tx] =
      tile[tx][ty];
}

__global__ __launch_bounds__(256) void k_gemm_qkv(
    const __bf16* __restrict__ xb, const __bf16* __restrict__ wt,
    __bf16* __restrict__ qb, __bf16* __restrict__ kb,
    __bf16* __restrict__ vt) {
  __shared__ __bf16 lsA[128 * 64], lsB[128 * 64];
  const int z = blockIdx.z;
  const int row0 = blockIdx.x * 128, col0 = blockIdx.y * 128;
  const __bf16* A0 = xb + (size_t)row0 * DD;
  const __bf16* B0 = wt + (size_t)z * DD * DD + (size_t)col0 * DD;

  f32x4 acc[4][4];
#pragma unroll
  for (int m = 0; m < 4; ++m)
#pragma unroll
    for (int n = 0; n < 4; ++n) acc[m][n] = (f32x4)0.0f;

  gemm_mainloop(A0, DD, B0, DD, DD, lsA, lsB, acc);

  const int t = threadIdx.x, lane = t & 63, w = t >> 6;
  const int wr = (w >> 1) * 64, wc = (w & 1) * 64;
  const int fr = lane & 15, fq = lane >> 4;

  if (z < 2) {
    __bf16* out = z ? kb : qb;
    const float scale = z ? 1.0f : 0.03125f;  // gamma = 1/sqrt(1024) into q
#pragma unroll
    for (int m = 0; m < 4; ++m)
#pragma unroll
      for (int n = 0; n < 4; ++n)
#pragma unroll
        for (int i = 0; i < 4; ++i) {
          const int gm = row0 + wr + m * 16 + fq * 4 + i;
          const int gn = col0 + wc + n * 16 + fr;
          out[(size_t)gm * DD + gn] = (__bf16)(acc[m][n][i] * scale);
        }
  } else {
    // vt[b][d][t] = v[b][t][d]
#pragma unroll
    for (int m = 0; m < 4; ++m)
#pragma unroll
      for (int n = 0; n < 4; ++n)
#pragma unroll
        for (int i = 0; i < 4; ++i) {
          const int gm = row0 + wr + m * 16 + fq * 4 + i;  // b*T + t
          const int b = gm >> 11, tl = gm & 2047;
          const int d = col0 + wc + n * 16 + fr;
          vt[((size_t)b * DD + d) * TT + tl] = (__bf16)acc[m][n][i];
        }
  }
}

__global__ __launch_bounds__(256) void k_gemm_scores(
    const __bf16* __restrict__ qb, const __bf16* __restrict__ kb,
    __bf16* __restrict__ Sb) {
  const int b = blockIdx.z;
  const int row0 = blockIdx.x * 128;  // query i tile
  const int col0 = blockIdx.y * 128;  // key j tile
  __bf16* St = Sb + (size_t)b * TT * TT;

  if (col0 > row0 + 127) {
    // entire tile above diagonal: multiplicative mask -> exact zeros
    const int4 z4 = {0, 0, 0, 0};
#pragma unroll
    for (int i = 0; i < 8; ++i) {
      const int e = (i * 256 + (int)threadIdx.x) * 8;
      const int r = e >> 7, c = e & 127;
      *reinterpret_cast<int4*>(&St[(size_t)(row0 + r) * TT + col0 + c]) = z4;
    }
    return;
  }

  __shared__ __bf16 lsA[128 * 64], lsB[128 * 64];
  const __bf16* A0 = qb + ((size_t)b * TT + row0) * DD;
  const __bf16* B0 = kb + ((size_t)b * TT + col0) * DD;

  f32x4 acc[4][4];
#pragma unroll
  for (int m = 0; m < 4; ++m)
#pragma unroll
    for (int n = 0; n < 4; ++n) acc[m][n] = (f32x4)0.0f;

  gemm_mainloop(A0, DD, B0, DD, DD, lsA, lsB, acc);

  const int t = threadIdx.x, lane = t & 63, w = t >> 6;
  const int wr = (w >> 1) * 64, wc = (w & 1) * 64;
  const int fr = lane & 15, fq = lane >> 4;
#pragma unroll
  for (int m = 0; m < 4; ++m)
#pragma unroll
    for (int n = 0; n < 4; ++n)
#pragma unroll
      for (int i = 0; i < 4; ++i) {
        const int gi = row0 + wr + m * 16 + fq * 4 + i;
        const int gj = col0 + wc + n * 16 + fr;
        float v = acc[m][n][i];       // gamma already folded into q
        if (gj > gi) v = 0.0f;        // multiplicative mask: exact 0
        St[(size_t)gi * TT + gj] = (__bf16)v;
      }
}

__global__ __launch_bounds__(256) void k_softmax(__bf16* __restrict__ Sb) {
  // one wave per row of 2048; masked zeros participate (exp(0-m)).
  const int row = blockIdx.x * 4 + (threadIdx.x >> 6);
  const int lane = threadIdx.x & 63;
  __bf16* S = Sb + (size_t)row * TT;

  float v[32];
#pragma unroll
  for (int c = 0; c < 4; ++c) {
    bf16x8v x = *reinterpret_cast<const bf16x8v*>(&S[c * 512 + lane * 8]);
#pragma unroll
    for (int j = 0; j < 8; ++j) v[c * 8 + j] = (float)x[j];
  }
  float m = -1e30f;
#pragma unroll
  for (int i = 0; i < 32; ++i) m = fmaxf(m, v[i]);
#pragma unroll
  for (int off = 32; off >= 1; off >>= 1) m = fmaxf(m, __shfl_xor(m, off));
  float l = 0.0f;
#pragma unroll
  for (int i = 0; i < 32; ++i) {
    v[i] = __expf(v[i] - m);
    l += v[i];
  }
#pragma unroll
  for (int off = 32; off >= 1; off >>= 1) l += __shfl_xor(l, off);
  const float inv = 1.0f / l;
#pragma unroll
  for (int c = 0; c < 4; ++c) {
    bf16x8v o;
#pragma unroll
    for (int j = 0; j < 8; ++j) o[j] = (__bf16)(v[c * 8 + j] * inv);
    *reinterpret_cast<bf16x8v*>(&S[c * 512 + lane * 8]) = o;
  }
}

__global__ __launch_bounds__(256) void k_gemm_pv(
    const __bf16* __restrict__ Sb, const __bf16* __restrict__ vt,
    float* __restrict__ out) {
  __shared__ __bf16 lsA[128 * 64], lsB[128 * 64];
  const int b = blockIdx.z;
  const int row0 = blockIdx.x * 128;  // query tile
  const int col0 = blockIdx.y * 128;  // d tile
  const __bf16* A0 = Sb + (size_t)b * TT * TT + (size_t)row0 * TT;
  const __bf16* B0 = vt + (size_t)b * DD * TT + (size_t)col0 * TT;

  f32x4 acc[4][4];
#pragma unroll
  for (int m = 0; m < 4; ++m)
#pragma unroll
    for (int n = 0; n < 4; ++n) acc[m][n] = (f32x4)0.0f;

  gemm_mainloop(A0, TT, B0, TT, TT, lsA, lsB, acc);

  const int t = threadIdx.x, lane = t & 63, w = t >> 6;
  const int wr = (w >> 1) * 64, wc = (w & 1) * 64;
  const int fr = lane & 15, fq = lane >> 4;
#pragma unroll
  for (int m = 0; m < 4; ++m)
#pragma unroll
    for (int n = 0; n < 4; ++n)
#pragma unroll
      for (int i = 0; i < 4; ++i) {
        const int gi = row0 + wr + m * 16 + fq * 4 + i;
        const int gd = col0 + wc + n * 16 + fr;
        out[((size_t)b * TT + gi) * DD + gd] = acc[m][n][i];
      }
}

// ---------------------------------------------------------------- launch
extern "C" void kernel_launch(void* const* d_in, const int* in_sizes, int n_in,
                              void* d_out, int out_size, void* d_ws,
                              size_t ws_size, hipStream_t stream) {
  const float* x  = (const float*)d_in[0];
  const float* wq = (const float*)d_in[1];
  const float* wk = (const float*)d_in[2];
  const float* wv = (const float*)d_in[3];
  float* out = (float*)d_out;

  char* ws = (char*)d_ws;
  __bf16* xb = (__bf16*)ws;                                  // 8192*1024
  __bf16* wt = xb + (size_t)BB * TT * DD;                    // 3*1024*1024
  __bf16* qb = wt + (size_t)3 * DD * DD;                     // 8192*1024
  __bf16* kb = qb + (size_t)BB * TT * DD;
  __bf16* vt = kb + (size_t)BB * TT * DD;                    // [b][d][t]
  __bf16* Sb = vt + (size_t)BB * TT * DD;                    // 4*2048*2048

  k_cast_x<<<2048, 256, 0, stream>>>((const float4*)x, (bf16x8v*)xb,
                                     BB * TT * DD / 8);
  k_transpose_w<<<dim3(32, 32, 3), dim3(32, 32), 0, stream>>>(wq, wk, wv, wt);
  k_gemm_qkv<<<dim3(64, 8, 3), 256, 0, stream>>>(xb, wt, qb, kb, vt);
  k_gemm_scores<<<dim3(16, 16, 4), 256, 0, stream>>>(qb, kb, Sb);
  k_softmax<<<2048, 256, 0, stream>>>(Sb);
  k_gemm_pv<<<dim3(16, 8, 4), 256, 0, stream>>>(Sb, vt, out);
}